// Round 1
// baseline (991.621 us; speedup 1.0000x reference)
//
#include <hip/hip_runtime.h>
#include <math.h>

// ---------------------------------------------------------------------------
// 2-layer GCN (PyG GCNConv semantics): self-loops, symmetric deg norm,
// linear, scatter-add aggregate, bias, ELU.
//   hs[n]  = (x @ W)[n] * dinv[n]
//   out[n] = elu( dinv[n] * (hs[n] + sum_{e:dst=n} hs[src_e]) + b )
// CSR (by dst) rebuilt every call in d_ws; deg includes self-loop so deg>=1.
// ---------------------------------------------------------------------------

__global__ void init_deg_cnt(float* __restrict__ deg, int* __restrict__ fill_cnt, int N) {
    int i = blockIdx.x * blockDim.x + threadIdx.x;
    if (i < N) { deg[i] = 1.0f; fill_cnt[i] = 0; }
}

__global__ void count_deg(const int* __restrict__ dst, float* __restrict__ deg, int E) {
    int i = blockIdx.x * blockDim.x + threadIdx.x;
    if (i < E) atomicAdd(&deg[dst[i]], 1.0f);
}

// Single-block two-level exclusive scan of (deg[i]-1) -> row_ptr[0..N]
__global__ void scan_rowptr(const float* __restrict__ deg, int* __restrict__ row_ptr, int N) {
    __shared__ int sums[256];
    int t = threadIdx.x;
    int chunk = (N + 255) / 256;
    int lo = t * chunk;
    int hi = min(lo + chunk, N);
    int s = 0;
    for (int i = lo; i < hi; ++i) s += (int)deg[i] - 1;
    sums[t] = s;
    __syncthreads();
    // Hillis-Steele inclusive scan over 256 partials
    for (int off = 1; off < 256; off <<= 1) {
        int v = (t >= off) ? sums[t - off] : 0;
        __syncthreads();
        sums[t] += v;
        __syncthreads();
    }
    int base = sums[t] - s;  // exclusive prefix of this thread's chunk
    for (int i = lo; i < hi; ++i) {
        row_ptr[i] = base;
        base += (int)deg[i] - 1;
    }
    if (t == 255) row_ptr[N] = base;  // == E
}

__global__ void compute_dinv(const float* __restrict__ deg, float* __restrict__ dinv, int N) {
    int i = blockIdx.x * blockDim.x + threadIdx.x;
    if (i < N) dinv[i] = rsqrtf(deg[i]);  // deg >= 1 always (self-loop)
}

__global__ void fill_csr(const int* __restrict__ src, const int* __restrict__ dst,
                         const int* __restrict__ row_ptr, int* __restrict__ fill_cnt,
                         int* __restrict__ col, int E) {
    int i = blockIdx.x * blockDim.x + threadIdx.x;
    if (i < E) {
        int d = dst[i];
        int p = row_ptr[d] + atomicAdd(&fill_cnt[d], 1);
        col[p] = src[i];
    }
}

// out[n][f] = dinv[n] * sum_k A[n][k] * W[k][f]   (K = 128 fixed)
// BM rows per block, F output cols; 256 threads; 4x4 register tile per thread.
template <int BM, int F>
__global__ __launch_bounds__(256) void gemm_scale(
    const float* __restrict__ A, const float* __restrict__ W,
    const float* __restrict__ dinv, float* __restrict__ out, int N) {
    __shared__ float As[BM][128];
    __shared__ float Ws[128][F];
    const int tid = threadIdx.x;
    const int n0 = blockIdx.x * BM;

    // stage W (128*F floats), float4
    for (int i = tid * 4; i < 128 * F; i += 256 * 4) {
        *(float4*)&((float*)Ws)[i] = *(const float4*)&W[i];
    }
    // stage A tile, float4 (rows past N zero-filled)
    for (int i = tid * 4; i < BM * 128; i += 256 * 4) {
        int r = i >> 7, k = i & 127;
        int n = n0 + r;
        float4 v = make_float4(0.f, 0.f, 0.f, 0.f);
        if (n < N) v = *(const float4*)&A[n * 128 + k];
        *(float4*)&As[r][k] = v;
    }
    __syncthreads();

    constexpr int TC = F / 4;      // threads along cols
    constexpr int TR = 256 / TC;   // threads along rows
    constexpr int RPT = BM / TR;   // rows per thread (== 4 for our configs)
    const int tc = tid % TC, tr = tid / TC;
    const int c0 = tc * 4;
    const int r0 = tr * RPT;

    float acc[RPT][4];
#pragma unroll
    for (int i = 0; i < RPT; ++i)
#pragma unroll
        for (int j = 0; j < 4; ++j) acc[i][j] = 0.f;

#pragma unroll 4
    for (int k = 0; k < 128; ++k) {
        float4 b = *(float4*)&Ws[k][c0];
#pragma unroll
        for (int i = 0; i < RPT; ++i) {
            float a = As[r0 + i][k];
            acc[i][0] += a * b.x;
            acc[i][1] += a * b.y;
            acc[i][2] += a * b.z;
            acc[i][3] += a * b.w;
        }
    }

#pragma unroll
    for (int i = 0; i < RPT; ++i) {
        int n = n0 + r0 + i;
        if (n < N) {
            float s = dinv[n];
            float4 o = make_float4(acc[i][0] * s, acc[i][1] * s, acc[i][2] * s, acc[i][3] * s);
            *(float4*)&out[n * F + c0] = o;
        }
    }
}

// out[n][d] = elu( dinv[n] * (hs[n][d] + sum_e hs[col[e]][d]) + bias[d] )
// 256 threads = (256/F) nodes per block; each node owned by F consecutive
// threads (F=128 -> 2 full waves/node, F=64 -> 1 wave/node: no intra-wave
// divergence on the degree loop).
template <int F>
__global__ __launch_bounds__(256) void agg_elu(
    const float* __restrict__ hs, const int* __restrict__ row_ptr,
    const int* __restrict__ col, const float* __restrict__ dinv,
    const float* __restrict__ bias, float* __restrict__ out, int N) {
    constexpr int G = 256 / F;
    const int g = threadIdx.x / F;
    const int d = threadIdx.x % F;
    const int n = blockIdx.x * G + g;
    if (n >= N) return;

    float acc = hs[n * F + d];  // self-loop term
    const int e0 = row_ptr[n], e1 = row_ptr[n + 1];
    for (int e = e0; e < e1; ++e) {
        int s = col[e];
        acc += hs[s * F + d];
    }
    float v = dinv[n] * acc + bias[d];
    out[n * F + d] = v > 0.f ? v : expm1f(v);
}

extern "C" void kernel_launch(void* const* d_in, const int* in_sizes, int n_in,
                              void* d_out, int out_size, void* d_ws, size_t ws_size,
                              hipStream_t stream) {
    const float* x  = (const float*)d_in[0];
    const int*   ei = (const int*)d_in[1];   // [2, E] int32 (JAX x64 off)
    const float* W1 = (const float*)d_in[2];
    const float* b1 = (const float*)d_in[3];
    const float* W2 = (const float*)d_in[4];
    const float* b2 = (const float*)d_in[5];
    float* out = (float*)d_out;

    const int N = in_sizes[0] / 128;
    const int E = in_sizes[1] / 2;
    const int* src = ei;
    const int* dst = ei + E;

    // workspace layout
    float* bufA = (float*)d_ws;            // N*128 floats (hs1, later hs2)
    float* bufB = bufA + (size_t)N * 128;  // N*128 floats (out1 = layer-1 output)
    float* deg  = bufB + (size_t)N * 128;  // N
    float* dinv = deg + N;                 // N
    int* row_ptr  = (int*)(dinv + N);      // N+1
    int* fill_cnt = row_ptr + N + 1;       // N
    int* col      = fill_cnt + N;          // E

    const int TB = 256;
    const int gN = (N + TB - 1) / TB;
    const int gE = (E + TB - 1) / TB;

    // graph build (every call; d_ws is re-poisoned)
    init_deg_cnt<<<gN, TB, 0, stream>>>(deg, fill_cnt, N);
    count_deg<<<gE, TB, 0, stream>>>(dst, deg, E);
    scan_rowptr<<<1, 256, 0, stream>>>(deg, row_ptr, N);
    compute_dinv<<<gN, TB, 0, stream>>>(deg, dinv, N);
    fill_csr<<<gE, TB, 0, stream>>>(src, dst, row_ptr, fill_cnt, col, E);

    // layer 1: hs1 = (x @ W1) * dinv ; out1 = elu(dinv*(agg hs1) + b1)
    gemm_scale<32, 128><<<(N + 31) / 32, 256, 0, stream>>>(x, W1, dinv, bufA, N);
    agg_elu<128><<<(N + 1) / 2, 256, 0, stream>>>(bufA, row_ptr, col, dinv, b1, bufB, N);

    // layer 2: hs2 = (out1 @ W2) * dinv ; out = elu(dinv*(agg hs2) + b2)
    gemm_scale<64, 64><<<(N + 63) / 64, 256, 0, stream>>>(bufB, W2, dinv, bufA, N);
    agg_elu<64><<<(N + 3) / 4, 256, 0, stream>>>(bufA, row_ptr, col, dinv, b2, out, N);
}

// Round 2
// 746.912 us; speedup vs baseline: 1.3276x; 1.3276x over previous
//
#include <hip/hip_runtime.h>
#include <math.h>

// ---------------------------------------------------------------------------
// 2-layer GCN (PyG GCNConv semantics): self-loops, symmetric deg norm,
// linear, scatter-add aggregate, bias, ELU.
//   hs[n]  = (x @ W)[n] * dinv[n]
//   out[n] = elu( dinv[n] * (hs[n] + sum_{e:dst=n} hs[src_e]) + b )
// CSR (by dst) rebuilt every call in d_ws; deg includes self-loop so deg>=1.
// R1: agg gather vectorized to float4 + 4x edge unroll (MLP for latency).
// ---------------------------------------------------------------------------

__global__ void init_deg_cnt(float* __restrict__ deg, int* __restrict__ fill_cnt, int N) {
    int i = blockIdx.x * blockDim.x + threadIdx.x;
    if (i < N) { deg[i] = 1.0f; fill_cnt[i] = 0; }
}

__global__ void count_deg(const int* __restrict__ dst, float* __restrict__ deg, int E) {
    int i = blockIdx.x * blockDim.x + threadIdx.x;
    if (i < E) atomicAdd(&deg[dst[i]], 1.0f);
}

// Single-block two-level exclusive scan of (deg[i]-1) -> row_ptr[0..N]
__global__ void scan_rowptr(const float* __restrict__ deg, int* __restrict__ row_ptr, int N) {
    __shared__ int sums[256];
    int t = threadIdx.x;
    int chunk = (N + 255) / 256;
    int lo = t * chunk;
    int hi = min(lo + chunk, N);
    int s = 0;
    for (int i = lo; i < hi; ++i) s += (int)deg[i] - 1;
    sums[t] = s;
    __syncthreads();
    for (int off = 1; off < 256; off <<= 1) {
        int v = (t >= off) ? sums[t - off] : 0;
        __syncthreads();
        sums[t] += v;
        __syncthreads();
    }
    int base = sums[t] - s;  // exclusive prefix of this thread's chunk
    for (int i = lo; i < hi; ++i) {
        row_ptr[i] = base;
        base += (int)deg[i] - 1;
    }
    if (t == 255) row_ptr[N] = base;  // == E
}

__global__ void compute_dinv(const float* __restrict__ deg, float* __restrict__ dinv, int N) {
    int i = blockIdx.x * blockDim.x + threadIdx.x;
    if (i < N) dinv[i] = rsqrtf(deg[i]);
}

__global__ void fill_csr(const int* __restrict__ src, const int* __restrict__ dst,
                         const int* __restrict__ row_ptr, int* __restrict__ fill_cnt,
                         int* __restrict__ col, int E) {
    int i = blockIdx.x * blockDim.x + threadIdx.x;
    if (i < E) {
        int d = dst[i];
        int p = row_ptr[d] + atomicAdd(&fill_cnt[d], 1);
        col[p] = src[i];
    }
}

// out[n][f] = dinv[n] * sum_k A[n][k] * W[k][f]   (K = 128 fixed)
template <int BM, int F>
__global__ __launch_bounds__(256) void gemm_scale(
    const float* __restrict__ A, const float* __restrict__ W,
    const float* __restrict__ dinv, float* __restrict__ out, int N) {
    __shared__ float As[BM][128];
    __shared__ float Ws[128][F];
    const int tid = threadIdx.x;
    const int n0 = blockIdx.x * BM;

    for (int i = tid * 4; i < 128 * F; i += 256 * 4) {
        *(float4*)&((float*)Ws)[i] = *(const float4*)&W[i];
    }
    for (int i = tid * 4; i < BM * 128; i += 256 * 4) {
        int r = i >> 7, k = i & 127;
        int n = n0 + r;
        float4 v = make_float4(0.f, 0.f, 0.f, 0.f);
        if (n < N) v = *(const float4*)&A[n * 128 + k];
        *(float4*)&As[r][k] = v;
    }
    __syncthreads();

    constexpr int TC = F / 4;
    constexpr int TR = 256 / TC;
    constexpr int RPT = BM / TR;
    const int tc = tid % TC, tr = tid / TC;
    const int c0 = tc * 4;
    const int r0 = tr * RPT;

    float acc[RPT][4];
#pragma unroll
    for (int i = 0; i < RPT; ++i)
#pragma unroll
        for (int j = 0; j < 4; ++j) acc[i][j] = 0.f;

#pragma unroll 4
    for (int k = 0; k < 128; ++k) {
        float4 b = *(float4*)&Ws[k][c0];
#pragma unroll
        for (int i = 0; i < RPT; ++i) {
            float a = As[r0 + i][k];
            acc[i][0] += a * b.x;
            acc[i][1] += a * b.y;
            acc[i][2] += a * b.z;
            acc[i][3] += a * b.w;
        }
    }

#pragma unroll
    for (int i = 0; i < RPT; ++i) {
        int n = n0 + r0 + i;
        if (n < N) {
            float s = dinv[n];
            float4 o = make_float4(acc[i][0] * s, acc[i][1] * s, acc[i][2] * s, acc[i][3] * s);
            *(float4*)&out[n * F + c0] = o;
        }
    }
}

__device__ __forceinline__ void add4(float4& a, const float4& b) {
    a.x += b.x; a.y += b.y; a.z += b.z; a.w += b.w;
}

// Vectorized gather-aggregate: F/4 threads per node, each owns 4 columns.
// 4x edge unroll -> 4 independent float4 gathers in flight per thread.
template <int F>
__global__ __launch_bounds__(256) void agg_elu_v4(
    const float* __restrict__ hs, const int* __restrict__ row_ptr,
    const int* __restrict__ col, const float* __restrict__ dinv,
    const float* __restrict__ bias, float* __restrict__ out, int N) {
    constexpr int TPN = F / 4;      // threads per node (32 @ F=128, 16 @ F=64)
    constexpr int NPB = 256 / TPN;  // nodes per block (8, 16)
    const int t = threadIdx.x % TPN;
    const int g = threadIdx.x / TPN;
    const int n = blockIdx.x * NPB + g;
    if (n >= N) return;
    const int c0 = t * 4;

    float4 acc0 = *(const float4*)&hs[(size_t)n * F + c0];  // self-loop term
    float4 acc1 = make_float4(0.f, 0.f, 0.f, 0.f);

    int e = row_ptr[n];
    const int e1 = row_ptr[n + 1];
    for (; e + 3 < e1; e += 4) {
        int s0 = col[e], s1 = col[e + 1], s2 = col[e + 2], s3 = col[e + 3];
        float4 a0 = *(const float4*)&hs[(size_t)s0 * F + c0];
        float4 a1 = *(const float4*)&hs[(size_t)s1 * F + c0];
        float4 a2 = *(const float4*)&hs[(size_t)s2 * F + c0];
        float4 a3 = *(const float4*)&hs[(size_t)s3 * F + c0];
        add4(acc0, a0); add4(acc1, a1); add4(acc0, a2); add4(acc1, a3);
    }
    for (; e < e1; ++e) {
        float4 a = *(const float4*)&hs[(size_t)col[e] * F + c0];
        add4(acc0, a);
    }
    add4(acc0, acc1);

    const float s = dinv[n];
    const float4 bb = *(const float4*)&bias[c0];
    float4 v;
    v.x = s * acc0.x + bb.x;
    v.y = s * acc0.y + bb.y;
    v.z = s * acc0.z + bb.z;
    v.w = s * acc0.w + bb.w;
    v.x = v.x > 0.f ? v.x : expm1f(v.x);
    v.y = v.y > 0.f ? v.y : expm1f(v.y);
    v.z = v.z > 0.f ? v.z : expm1f(v.z);
    v.w = v.w > 0.f ? v.w : expm1f(v.w);
    *(float4*)&out[(size_t)n * F + c0] = v;
}

extern "C" void kernel_launch(void* const* d_in, const int* in_sizes, int n_in,
                              void* d_out, int out_size, void* d_ws, size_t ws_size,
                              hipStream_t stream) {
    const float* x  = (const float*)d_in[0];
    const int*   ei = (const int*)d_in[1];   // [2, E] int32
    const float* W1 = (const float*)d_in[2];
    const float* b1 = (const float*)d_in[3];
    const float* W2 = (const float*)d_in[4];
    const float* b2 = (const float*)d_in[5];
    float* out = (float*)d_out;

    const int N = in_sizes[0] / 128;
    const int E = in_sizes[1] / 2;
    const int* src = ei;
    const int* dst = ei + E;

    float* bufA = (float*)d_ws;            // N*128 floats
    float* bufB = bufA + (size_t)N * 128;  // N*128 floats
    float* deg  = bufB + (size_t)N * 128;  // N
    float* dinv = deg + N;                 // N
    int* row_ptr  = (int*)(dinv + N);      // N+1
    int* fill_cnt = row_ptr + N + 1;       // N
    int* col      = fill_cnt + N;          // E

    const int TB = 256;
    const int gN = (N + TB - 1) / TB;
    const int gE = (E + TB - 1) / TB;

    init_deg_cnt<<<gN, TB, 0, stream>>>(deg, fill_cnt, N);
    count_deg<<<gE, TB, 0, stream>>>(dst, deg, E);
    scan_rowptr<<<1, 256, 0, stream>>>(deg, row_ptr, N);
    compute_dinv<<<gN, TB, 0, stream>>>(deg, dinv, N);
    fill_csr<<<gE, TB, 0, stream>>>(src, dst, row_ptr, fill_cnt, col, E);

    // layer 1
    gemm_scale<32, 128><<<(N + 31) / 32, 256, 0, stream>>>(x, W1, dinv, bufA, N);
    agg_elu_v4<128><<<(N + 7) / 8, 256, 0, stream>>>(bufA, row_ptr, col, dinv, b1, bufB, N);

    // layer 2
    gemm_scale<64, 64><<<(N + 63) / 64, 256, 0, stream>>>(bufB, W2, dinv, bufA, N);
    agg_elu_v4<64><<<(N + 15) / 16, 256, 0, stream>>>(bufA, row_ptr, col, dinv, b2, out, N);
}

// Round 3
// 581.487 us; speedup vs baseline: 1.7053x; 1.2845x over previous
//
#include <hip/hip_runtime.h>
#include <math.h>

// ---------------------------------------------------------------------------
// 2-layer GCN (PyG GCNConv semantics): self-loops, symmetric deg norm,
// linear, scatter-add aggregate, bias, ELU.
//   hs[n]  = (x @ W)[n] * dinv[n]
//   out[n] = elu( dinv[n] * (hs[n] + sum_{e:dst=n} hs[src_e]) + b )
// CSR (by dst) rebuilt every call in d_ws; deg includes self-loop so deg>=1.
// R1: agg gather float4 + 4x edge unroll.
// R2: single-block scan (167us serial!) -> 3-phase device-wide scan (~10us),
//     dinv fused into scan phase 1.
// ---------------------------------------------------------------------------

#define SCAN_TPB 256
#define SCAN_VPT 4
#define SCAN_CHUNK (SCAN_TPB * SCAN_VPT)  // 1024 elements per block

__global__ void init_deg_cnt(float* __restrict__ deg, int* __restrict__ fill_cnt, int N) {
    int i = blockIdx.x * blockDim.x + threadIdx.x;
    if (i < N) { deg[i] = 1.0f; fill_cnt[i] = 0; }
}

__global__ void count_deg(const int* __restrict__ dst, float* __restrict__ deg, int E) {
    int i = blockIdx.x * blockDim.x + threadIdx.x;
    if (i < E) atomicAdd(&deg[dst[i]], 1.0f);
}

// Scan phase 1: per-block sum of (deg[i]-1) -> partial[b]; fused dinv.
__global__ __launch_bounds__(SCAN_TPB) void deg_partial_dinv(
    const float* __restrict__ deg, float* __restrict__ dinv,
    int* __restrict__ partial, int N) {
    const int t = threadIdx.x;
    const int base = blockIdx.x * SCAN_CHUNK + t * SCAN_VPT;
    int s = 0;
#pragma unroll
    for (int j = 0; j < SCAN_VPT; ++j) {
        int i = base + j;
        if (i < N) {
            float d = deg[i];
            dinv[i] = rsqrtf(d);
            s += (int)d - 1;
        }
    }
    __shared__ int sums[SCAN_TPB];
    sums[t] = s;
    __syncthreads();
    for (int off = SCAN_TPB / 2; off > 0; off >>= 1) {
        if (t < off) sums[t] += sums[t + off];
        __syncthreads();
    }
    if (t == 0) partial[blockIdx.x] = sums[0];
}

// Scan phase 2: exclusive scan of partials (nb <= 256), write row_ptr[N]=E.
__global__ __launch_bounds__(SCAN_TPB) void scan_partials(
    int* __restrict__ partial, int* __restrict__ row_ptr, int nb, int N) {
    __shared__ int sh[SCAN_TPB];
    const int t = threadIdx.x;
    int v = (t < nb) ? partial[t] : 0;
    sh[t] = v;
    __syncthreads();
    for (int off = 1; off < SCAN_TPB; off <<= 1) {
        int u = (t >= off) ? sh[t - off] : 0;
        __syncthreads();
        sh[t] += u;
        __syncthreads();
    }
    if (t < nb) partial[t] = sh[t] - v;      // exclusive prefix
    if (t == 0) row_ptr[N] = sh[nb - 1];     // total == E
}

// Scan phase 3: intra-block exclusive scan + block offset -> row_ptr[i].
__global__ __launch_bounds__(SCAN_TPB) void scan_write_rowptr(
    const float* __restrict__ deg, const int* __restrict__ partial,
    int* __restrict__ row_ptr, int N) {
    const int t = threadIdx.x;
    const int base = blockIdx.x * SCAN_CHUNK + t * SCAN_VPT;
    int vals[SCAN_VPT];
    int s = 0;
#pragma unroll
    for (int j = 0; j < SCAN_VPT; ++j) {
        int i = base + j;
        vals[j] = (i < N) ? (int)deg[i] - 1 : 0;
        s += vals[j];
    }
    __shared__ int sums[SCAN_TPB];
    sums[t] = s;
    __syncthreads();
    for (int off = 1; off < SCAN_TPB; off <<= 1) {
        int u = (t >= off) ? sums[t - off] : 0;
        __syncthreads();
        sums[t] += u;
        __syncthreads();
    }
    int excl = sums[t] - s + partial[blockIdx.x];
#pragma unroll
    for (int j = 0; j < SCAN_VPT; ++j) {
        int i = base + j;
        if (i < N) { row_ptr[i] = excl; excl += vals[j]; }
    }
}

__global__ void fill_csr(const int* __restrict__ src, const int* __restrict__ dst,
                         const int* __restrict__ row_ptr, int* __restrict__ fill_cnt,
                         int* __restrict__ col, int E) {
    int i = blockIdx.x * blockDim.x + threadIdx.x;
    if (i < E) {
        int d = dst[i];
        int p = row_ptr[d] + atomicAdd(&fill_cnt[d], 1);
        col[p] = src[i];
    }
}

// out[n][f] = dinv[n] * sum_k A[n][k] * W[k][f]   (K = 128 fixed)
template <int BM, int F>
__global__ __launch_bounds__(256) void gemm_scale(
    const float* __restrict__ A, const float* __restrict__ W,
    const float* __restrict__ dinv, float* __restrict__ out, int N) {
    __shared__ float As[BM][128];
    __shared__ float Ws[128][F];
    const int tid = threadIdx.x;
    const int n0 = blockIdx.x * BM;

    for (int i = tid * 4; i < 128 * F; i += 256 * 4) {
        *(float4*)&((float*)Ws)[i] = *(const float4*)&W[i];
    }
    for (int i = tid * 4; i < BM * 128; i += 256 * 4) {
        int r = i >> 7, k = i & 127;
        int n = n0 + r;
        float4 v = make_float4(0.f, 0.f, 0.f, 0.f);
        if (n < N) v = *(const float4*)&A[n * 128 + k];
        *(float4*)&As[r][k] = v;
    }
    __syncthreads();

    constexpr int TC = F / 4;
    constexpr int TR = 256 / TC;
    constexpr int RPT = BM / TR;
    const int tc = tid % TC, tr = tid / TC;
    const int c0 = tc * 4;
    const int r0 = tr * RPT;

    float acc[RPT][4];
#pragma unroll
    for (int i = 0; i < RPT; ++i)
#pragma unroll
        for (int j = 0; j < 4; ++j) acc[i][j] = 0.f;

#pragma unroll 4
    for (int k = 0; k < 128; ++k) {
        float4 b = *(float4*)&Ws[k][c0];
#pragma unroll
        for (int i = 0; i < RPT; ++i) {
            float a = As[r0 + i][k];
            acc[i][0] += a * b.x;
            acc[i][1] += a * b.y;
            acc[i][2] += a * b.z;
            acc[i][3] += a * b.w;
        }
    }

#pragma unroll
    for (int i = 0; i < RPT; ++i) {
        int n = n0 + r0 + i;
        if (n < N) {
            float s = dinv[n];
            float4 o = make_float4(acc[i][0] * s, acc[i][1] * s, acc[i][2] * s, acc[i][3] * s);
            *(float4*)&out[n * F + c0] = o;
        }
    }
}

__device__ __forceinline__ void add4(float4& a, const float4& b) {
    a.x += b.x; a.y += b.y; a.z += b.z; a.w += b.w;
}

// Vectorized gather-aggregate: F/4 threads per node, each owns 4 columns.
template <int F>
__global__ __launch_bounds__(256) void agg_elu_v4(
    const float* __restrict__ hs, const int* __restrict__ row_ptr,
    const int* __restrict__ col, const float* __restrict__ dinv,
    const float* __restrict__ bias, float* __restrict__ out, int N) {
    constexpr int TPN = F / 4;
    constexpr int NPB = 256 / TPN;
    const int t = threadIdx.x % TPN;
    const int g = threadIdx.x / TPN;
    const int n = blockIdx.x * NPB + g;
    if (n >= N) return;
    const int c0 = t * 4;

    float4 acc0 = *(const float4*)&hs[(size_t)n * F + c0];  // self-loop term
    float4 acc1 = make_float4(0.f, 0.f, 0.f, 0.f);

    int e = row_ptr[n];
    const int e1 = row_ptr[n + 1];
    for (; e + 3 < e1; e += 4) {
        int s0 = col[e], s1 = col[e + 1], s2 = col[e + 2], s3 = col[e + 3];
        float4 a0 = *(const float4*)&hs[(size_t)s0 * F + c0];
        float4 a1 = *(const float4*)&hs[(size_t)s1 * F + c0];
        float4 a2 = *(const float4*)&hs[(size_t)s2 * F + c0];
        float4 a3 = *(const float4*)&hs[(size_t)s3 * F + c0];
        add4(acc0, a0); add4(acc1, a1); add4(acc0, a2); add4(acc1, a3);
    }
    for (; e < e1; ++e) {
        float4 a = *(const float4*)&hs[(size_t)col[e] * F + c0];
        add4(acc0, a);
    }
    add4(acc0, acc1);

    const float s = dinv[n];
    const float4 bb = *(const float4*)&bias[c0];
    float4 v;
    v.x = s * acc0.x + bb.x;
    v.y = s * acc0.y + bb.y;
    v.z = s * acc0.z + bb.z;
    v.w = s * acc0.w + bb.w;
    v.x = v.x > 0.f ? v.x : expm1f(v.x);
    v.y = v.y > 0.f ? v.y : expm1f(v.y);
    v.z = v.z > 0.f ? v.z : expm1f(v.z);
    v.w = v.w > 0.f ? v.w : expm1f(v.w);
    *(float4*)&out[(size_t)n * F + c0] = v;
}

extern "C" void kernel_launch(void* const* d_in, const int* in_sizes, int n_in,
                              void* d_out, int out_size, void* d_ws, size_t ws_size,
                              hipStream_t stream) {
    const float* x  = (const float*)d_in[0];
    const int*   ei = (const int*)d_in[1];   // [2, E] int32
    const float* W1 = (const float*)d_in[2];
    const float* b1 = (const float*)d_in[3];
    const float* W2 = (const float*)d_in[4];
    const float* b2 = (const float*)d_in[5];
    float* out = (float*)d_out;

    const int N = in_sizes[0] / 128;
    const int E = in_sizes[1] / 2;
    const int* src = ei;
    const int* dst = ei + E;

    float* bufA = (float*)d_ws;            // N*128 floats
    float* bufB = bufA + (size_t)N * 128;  // N*128 floats
    float* deg  = bufB + (size_t)N * 128;  // N
    float* dinv = deg + N;                 // N
    int* row_ptr  = (int*)(dinv + N);      // N+1
    int* fill_cnt = row_ptr + N + 1;       // N
    int* col      = fill_cnt + N;          // E
    int* partial  = col + E;               // scan partials (<=256)

    const int TB = 256;
    const int gN = (N + TB - 1) / TB;
    const int gE = (E + TB - 1) / TB;
    const int nb = (N + SCAN_CHUNK - 1) / SCAN_CHUNK;  // 98 blocks @ N=100K

    init_deg_cnt<<<gN, TB, 0, stream>>>(deg, fill_cnt, N);
    count_deg<<<gE, TB, 0, stream>>>(dst, deg, E);
    deg_partial_dinv<<<nb, SCAN_TPB, 0, stream>>>(deg, dinv, partial, N);
    scan_partials<<<1, SCAN_TPB, 0, stream>>>(partial, row_ptr, nb, N);
    scan_write_rowptr<<<nb, SCAN_TPB, 0, stream>>>(deg, partial, row_ptr, N);
    fill_csr<<<gE, TB, 0, stream>>>(src, dst, row_ptr, fill_cnt, col, E);

    // layer 1
    gemm_scale<32, 128><<<(N + 31) / 32, 256, 0, stream>>>(x, W1, dinv, bufA, N);
    agg_elu_v4<128><<<(N + 7) / 8, 256, 0, stream>>>(bufA, row_ptr, col, dinv, b1, bufB, N);

    // layer 2
    gemm_scale<64, 64><<<(N + 63) / 64, 256, 0, stream>>>(bufB, W2, dinv, bufA, N);
    agg_elu_v4<64><<<(N + 15) / 16, 256, 0, stream>>>(bufA, row_ptr, col, dinv, b2, out, N);
}

// Round 4
// 552.866 us; speedup vs baseline: 1.7936x; 1.0518x over previous
//
#include <hip/hip_runtime.h>
#include <math.h>

// ---------------------------------------------------------------------------
// 2-layer GCN (PyG GCNConv semantics): self-loops, symmetric deg norm,
// linear, scatter-add aggregate, bias, ELU.
//   hs[n]  = (x @ W)[n] * dinv[n]
//   out[n] = elu( dinv[n] * (hs[n] + sum_{e:dst=n} hs[src_e]) + b )
// CSR (by dst) rebuilt every call in d_ws.
// R1: agg gather float4 + 4x edge unroll.
// R2: 3-phase device-wide scan, dinv fused.
// R3 (this): agg = one wave per node (edge-parallel segments, no divergence
//     waste, 2x rows in flight, shfl-combine); GEMM float4 A-reads.
// ---------------------------------------------------------------------------

#define SCAN_TPB 256
#define SCAN_VPT 4
#define SCAN_CHUNK (SCAN_TPB * SCAN_VPT)  // 1024 elements per block

__global__ void init_deg_cnt(float* __restrict__ deg, int* __restrict__ fill_cnt, int N) {
    int i = blockIdx.x * blockDim.x + threadIdx.x;
    if (i < N) { deg[i] = 1.0f; fill_cnt[i] = 0; }
}

__global__ void count_deg(const int* __restrict__ dst, float* __restrict__ deg, int E) {
    int i = blockIdx.x * blockDim.x + threadIdx.x;
    if (i < E) atomicAdd(&deg[dst[i]], 1.0f);
}

// Scan phase 1: per-block sum of (deg[i]-1) -> partial[b]; fused dinv.
__global__ __launch_bounds__(SCAN_TPB) void deg_partial_dinv(
    const float* __restrict__ deg, float* __restrict__ dinv,
    int* __restrict__ partial, int N) {
    const int t = threadIdx.x;
    const int base = blockIdx.x * SCAN_CHUNK + t * SCAN_VPT;
    int s = 0;
#pragma unroll
    for (int j = 0; j < SCAN_VPT; ++j) {
        int i = base + j;
        if (i < N) {
            float d = deg[i];
            dinv[i] = rsqrtf(d);
            s += (int)d - 1;
        }
    }
    __shared__ int sums[SCAN_TPB];
    sums[t] = s;
    __syncthreads();
    for (int off = SCAN_TPB / 2; off > 0; off >>= 1) {
        if (t < off) sums[t] += sums[t + off];
        __syncthreads();
    }
    if (t == 0) partial[blockIdx.x] = sums[0];
}

// Scan phase 2: exclusive scan of partials (nb <= 256), write row_ptr[N]=E.
__global__ __launch_bounds__(SCAN_TPB) void scan_partials(
    int* __restrict__ partial, int* __restrict__ row_ptr, int nb, int N) {
    __shared__ int sh[SCAN_TPB];
    const int t = threadIdx.x;
    int v = (t < nb) ? partial[t] : 0;
    sh[t] = v;
    __syncthreads();
    for (int off = 1; off < SCAN_TPB; off <<= 1) {
        int u = (t >= off) ? sh[t - off] : 0;
        __syncthreads();
        sh[t] += u;
        __syncthreads();
    }
    if (t < nb) partial[t] = sh[t] - v;
    if (t == 0) row_ptr[N] = sh[nb - 1];
}

// Scan phase 3: intra-block exclusive scan + block offset -> row_ptr[i].
__global__ __launch_bounds__(SCAN_TPB) void scan_write_rowptr(
    const float* __restrict__ deg, const int* __restrict__ partial,
    int* __restrict__ row_ptr, int N) {
    const int t = threadIdx.x;
    const int base = blockIdx.x * SCAN_CHUNK + t * SCAN_VPT;
    int vals[SCAN_VPT];
    int s = 0;
#pragma unroll
    for (int j = 0; j < SCAN_VPT; ++j) {
        int i = base + j;
        vals[j] = (i < N) ? (int)deg[i] - 1 : 0;
        s += vals[j];
    }
    __shared__ int sums[SCAN_TPB];
    sums[t] = s;
    __syncthreads();
    for (int off = 1; off < SCAN_TPB; off <<= 1) {
        int u = (t >= off) ? sums[t - off] : 0;
        __syncthreads();
        sums[t] += u;
        __syncthreads();
    }
    int excl = sums[t] - s + partial[blockIdx.x];
#pragma unroll
    for (int j = 0; j < SCAN_VPT; ++j) {
        int i = base + j;
        if (i < N) { row_ptr[i] = excl; excl += vals[j]; }
    }
}

__global__ void fill_csr(const int* __restrict__ src, const int* __restrict__ dst,
                         const int* __restrict__ row_ptr, int* __restrict__ fill_cnt,
                         int* __restrict__ col, int E) {
    int i = blockIdx.x * blockDim.x + threadIdx.x;
    if (i < E) {
        int d = dst[i];
        int p = row_ptr[d] + atomicAdd(&fill_cnt[d], 1);
        col[p] = src[i];
    }
}

// out[n][f] = dinv[n] * sum_k A[n][k] * W[k][f]   (K = 128 fixed)
// float4 A-reads over 4 k-steps; As padded only at F=64 (4-way bank fix;
// F=128 As reads are half-wave-uniform broadcasts and pad would break
// the 2-blocks/CU LDS fit at 80KB).
template <int BM, int F>
__global__ __launch_bounds__(256) void gemm_scale(
    const float* __restrict__ A, const float* __restrict__ W,
    const float* __restrict__ dinv, float* __restrict__ out, int N) {
    constexpr int APAD = (F == 64) ? 4 : 0;
    __shared__ float As[BM][128 + APAD];
    __shared__ float Ws[128][F];
    const int tid = threadIdx.x;
    const int n0 = blockIdx.x * BM;

    for (int i = tid * 4; i < 128 * F; i += 256 * 4) {
        *(float4*)&((float*)Ws)[i] = *(const float4*)&W[i];
    }
    for (int i = tid * 4; i < BM * 128; i += 256 * 4) {
        int r = i >> 7, k = i & 127;
        int n = n0 + r;
        float4 v = make_float4(0.f, 0.f, 0.f, 0.f);
        if (n < N) v = *(const float4*)&A[n * 128 + k];
        *(float4*)&As[r][k] = v;
    }
    __syncthreads();

    constexpr int TC = F / 4;
    constexpr int TR = 256 / TC;
    constexpr int RPT = BM / TR;
    const int tc = tid % TC, tr = tid / TC;
    const int c0 = tc * 4;
    const int r0 = tr * RPT;

    float acc[RPT][4];
#pragma unroll
    for (int i = 0; i < RPT; ++i)
#pragma unroll
        for (int j = 0; j < 4; ++j) acc[i][j] = 0.f;

#pragma unroll 2
    for (int k4 = 0; k4 < 128; k4 += 4) {
        float4 a[RPT];
#pragma unroll
        for (int i = 0; i < RPT; ++i) a[i] = *(const float4*)&As[r0 + i][k4];
#pragma unroll
        for (int j = 0; j < 4; ++j) {
            float4 b = *(const float4*)&Ws[k4 + j][c0];
#pragma unroll
            for (int i = 0; i < RPT; ++i) {
                float aj = ((const float*)&a[i])[j];
                acc[i][0] += aj * b.x;
                acc[i][1] += aj * b.y;
                acc[i][2] += aj * b.z;
                acc[i][3] += aj * b.w;
            }
        }
    }

#pragma unroll
    for (int i = 0; i < RPT; ++i) {
        int n = n0 + r0 + i;
        if (n < N) {
            float s = dinv[n];
            float4 o = make_float4(acc[i][0] * s, acc[i][1] * s, acc[i][2] * s, acc[i][3] * s);
            *(float4*)&out[n * F + c0] = o;
        }
    }
}

__device__ __forceinline__ void add4(float4& a, const float4& b) {
    a.x += b.x; a.y += b.y; a.z += b.z; a.w += b.w;
}
__device__ __forceinline__ float4 ld4(const float* p) { return *(const float4*)p; }

// One WAVE per node. NSEG = 64/(F/4) edge-parallel segments process edges
// e, e+1[, e+2, e+3] of the SAME node -> loop trip deg/NSEG, wave-uniform
// (no half-wave divergence waste), 4 gathers in flight per lane
// (4*NSEG rows in flight per node). Butterfly shfl-combine across segments.
template <int F>
__global__ __launch_bounds__(256) void agg_elu_wave(
    const float* __restrict__ hs, const int* __restrict__ row_ptr,
    const int* __restrict__ col, const float* __restrict__ dinv,
    const float* __restrict__ bias, float* __restrict__ out, int N) {
    constexpr int TPN = F / 4;      // lanes per feature row (32 @128, 16 @64)
    constexpr int NSEG = 64 / TPN;  // segments per wave (2, 4)
    const int wave = threadIdx.x >> 6;
    const int lane = threadIdx.x & 63;
    const int seg = lane / TPN;
    const int t = lane % TPN;
    const int c0 = t * 4;
    const int n = blockIdx.x * 4 + wave;
    if (n >= N) return;

    const int e0 = row_ptr[n];
    const int e1 = row_ptr[n + 1];
    float4 acc0 = make_float4(0.f, 0.f, 0.f, 0.f);
    float4 acc1 = make_float4(0.f, 0.f, 0.f, 0.f);

    int e = e0 + seg;
    for (; e + 3 * NSEG < e1; e += 4 * NSEG) {
        int s0 = col[e];
        int s1 = col[e + NSEG];
        int s2 = col[e + 2 * NSEG];
        int s3 = col[e + 3 * NSEG];
        float4 a0 = ld4(&hs[(size_t)s0 * F + c0]);
        float4 a1 = ld4(&hs[(size_t)s1 * F + c0]);
        float4 a2 = ld4(&hs[(size_t)s2 * F + c0]);
        float4 a3 = ld4(&hs[(size_t)s3 * F + c0]);
        add4(acc0, a0); add4(acc1, a1); add4(acc0, a2); add4(acc1, a3);
    }
    for (; e < e1; e += NSEG) {
        add4(acc0, ld4(&hs[(size_t)col[e] * F + c0]));
    }
    add4(acc0, acc1);

    // combine segments (same node, same columns) via butterfly
#pragma unroll
    for (int off = TPN; off < 64; off <<= 1) {
        acc0.x += __shfl_xor(acc0.x, off, 64);
        acc0.y += __shfl_xor(acc0.y, off, 64);
        acc0.z += __shfl_xor(acc0.z, off, 64);
        acc0.w += __shfl_xor(acc0.w, off, 64);
    }

    if (seg == 0) {
        float4 self = ld4(&hs[(size_t)n * F + c0]);
        add4(acc0, self);
        const float s = dinv[n];
        const float4 bb = ld4(&bias[c0]);
        float4 v;
        v.x = s * acc0.x + bb.x;
        v.y = s * acc0.y + bb.y;
        v.z = s * acc0.z + bb.z;
        v.w = s * acc0.w + bb.w;
        v.x = v.x > 0.f ? v.x : expm1f(v.x);
        v.y = v.y > 0.f ? v.y : expm1f(v.y);
        v.z = v.z > 0.f ? v.z : expm1f(v.z);
        v.w = v.w > 0.f ? v.w : expm1f(v.w);
        *(float4*)&out[(size_t)n * F + c0] = v;
    }
}

extern "C" void kernel_launch(void* const* d_in, const int* in_sizes, int n_in,
                              void* d_out, int out_size, void* d_ws, size_t ws_size,
                              hipStream_t stream) {
    const float* x  = (const float*)d_in[0];
    const int*   ei = (const int*)d_in[1];   // [2, E] int32
    const float* W1 = (const float*)d_in[2];
    const float* b1 = (const float*)d_in[3];
    const float* W2 = (const float*)d_in[4];
    const float* b2 = (const float*)d_in[5];
    float* out = (float*)d_out;

    const int N = in_sizes[0] / 128;
    const int E = in_sizes[1] / 2;
    const int* src = ei;
    const int* dst = ei + E;

    float* bufA = (float*)d_ws;            // N*128 floats
    float* bufB = bufA + (size_t)N * 128;  // N*128 floats
    float* deg  = bufB + (size_t)N * 128;  // N
    float* dinv = deg + N;                 // N
    int* row_ptr  = (int*)(dinv + N);      // N+1
    int* fill_cnt = row_ptr + N + 1;       // N
    int* col      = fill_cnt + N;          // E
    int* partial  = col + E;               // scan partials (<=256)

    const int TB = 256;
    const int gN = (N + TB - 1) / TB;
    const int gE = (E + TB - 1) / TB;
    const int nb = (N + SCAN_CHUNK - 1) / SCAN_CHUNK;

    init_deg_cnt<<<gN, TB, 0, stream>>>(deg, fill_cnt, N);
    count_deg<<<gE, TB, 0, stream>>>(dst, deg, E);
    deg_partial_dinv<<<nb, SCAN_TPB, 0, stream>>>(deg, dinv, partial, N);
    scan_partials<<<1, SCAN_TPB, 0, stream>>>(partial, row_ptr, nb, N);
    scan_write_rowptr<<<nb, SCAN_TPB, 0, stream>>>(deg, partial, row_ptr, N);
    fill_csr<<<gE, TB, 0, stream>>>(src, dst, row_ptr, fill_cnt, col, E);

    // layer 1
    gemm_scale<32, 128><<<(N + 31) / 32, 256, 0, stream>>>(x, W1, dinv, bufA, N);
    agg_elu_wave<128><<<(N + 3) / 4, 256, 0, stream>>>(bufA, row_ptr, col, dinv, b1, bufB, N);

    // layer 2
    gemm_scale<64, 64><<<(N + 63) / 64, 256, 0, stream>>>(bufB, W2, dinv, bufA, N);
    agg_elu_wave<64><<<(N + 3) / 4, 256, 0, stream>>>(bufA, row_ptr, col, dinv, b2, out, N);
}

// Round 5
// 514.857 us; speedup vs baseline: 1.9260x; 1.0738x over previous
//
#include <hip/hip_runtime.h>
#include <math.h>

// ---------------------------------------------------------------------------
// 2-layer GCN (PyG GCNConv semantics): self-loops, symmetric deg norm,
// linear, scatter-add aggregate, bias, ELU.
//   hs[n]  = (x @ W)[n] * dinv[n]      (stored bf16 — the gathered array)
//   out[n] = elu( dinv[n] * (hs[n] + sum_{e:dst=n} hs[src_e]) + b )
// CSR (by dst) rebuilt every call in d_ws.
// R1: agg gather float4 + 4x edge unroll.
// R2: 3-phase device-wide scan, dinv fused.
// R3: one wave per node, edge-parallel segments, shfl combine.
// R4 (this): hs stored bf16 (RNE) -> halves the 8-XCD L2-fill traffic that
//     R3 showed to be the supply wall (119us @ 400MB FETCH, MLP-insensitive).
//     fp32 accumulation everywhere; out1 / final output stay fp32.
// ---------------------------------------------------------------------------

#define SCAN_TPB 256
#define SCAN_VPT 4
#define SCAN_CHUNK (SCAN_TPB * SCAN_VPT)  // 1024 elements per block

typedef unsigned int uint32_tt;
typedef unsigned short ushort_tt;

__device__ __forceinline__ ushort_tt f2bf_rne(float f) {
    uint32_tt u = __float_as_uint(f);
    u += 0x7FFFu + ((u >> 16) & 1u);  // round-to-nearest-even
    return (ushort_tt)(u >> 16);
}
__device__ __forceinline__ float bflo(uint32_tt u) { return __uint_as_float(u << 16); }
__device__ __forceinline__ float bfhi(uint32_tt u) { return __uint_as_float(u & 0xFFFF0000u); }

__global__ void init_deg_cnt(float* __restrict__ deg, int* __restrict__ fill_cnt, int N) {
    int i = blockIdx.x * blockDim.x + threadIdx.x;
    if (i < N) { deg[i] = 1.0f; fill_cnt[i] = 0; }
}

__global__ void count_deg(const int* __restrict__ dst, float* __restrict__ deg, int E) {
    int i = blockIdx.x * blockDim.x + threadIdx.x;
    if (i < E) atomicAdd(&deg[dst[i]], 1.0f);
}

// Scan phase 1: per-block sum of (deg[i]-1) -> partial[b]; fused dinv.
__global__ __launch_bounds__(SCAN_TPB) void deg_partial_dinv(
    const float* __restrict__ deg, float* __restrict__ dinv,
    int* __restrict__ partial, int N) {
    const int t = threadIdx.x;
    const int base = blockIdx.x * SCAN_CHUNK + t * SCAN_VPT;
    int s = 0;
#pragma unroll
    for (int j = 0; j < SCAN_VPT; ++j) {
        int i = base + j;
        if (i < N) {
            float d = deg[i];
            dinv[i] = rsqrtf(d);
            s += (int)d - 1;
        }
    }
    __shared__ int sums[SCAN_TPB];
    sums[t] = s;
    __syncthreads();
    for (int off = SCAN_TPB / 2; off > 0; off >>= 1) {
        if (t < off) sums[t] += sums[t + off];
        __syncthreads();
    }
    if (t == 0) partial[blockIdx.x] = sums[0];
}

// Scan phase 2: exclusive scan of partials (nb <= 256), write row_ptr[N]=E.
__global__ __launch_bounds__(SCAN_TPB) void scan_partials(
    int* __restrict__ partial, int* __restrict__ row_ptr, int nb, int N) {
    __shared__ int sh[SCAN_TPB];
    const int t = threadIdx.x;
    int v = (t < nb) ? partial[t] : 0;
    sh[t] = v;
    __syncthreads();
    for (int off = 1; off < SCAN_TPB; off <<= 1) {
        int u = (t >= off) ? sh[t - off] : 0;
        __syncthreads();
        sh[t] += u;
        __syncthreads();
    }
    if (t < nb) partial[t] = sh[t] - v;
    if (t == 0) row_ptr[N] = sh[nb - 1];
}

// Scan phase 3: intra-block exclusive scan + block offset -> row_ptr[i].
__global__ __launch_bounds__(SCAN_TPB) void scan_write_rowptr(
    const float* __restrict__ deg, const int* __restrict__ partial,
    int* __restrict__ row_ptr, int N) {
    const int t = threadIdx.x;
    const int base = blockIdx.x * SCAN_CHUNK + t * SCAN_VPT;
    int vals[SCAN_VPT];
    int s = 0;
#pragma unroll
    for (int j = 0; j < SCAN_VPT; ++j) {
        int i = base + j;
        vals[j] = (i < N) ? (int)deg[i] - 1 : 0;
        s += vals[j];
    }
    __shared__ int sums[SCAN_TPB];
    sums[t] = s;
    __syncthreads();
    for (int off = 1; off < SCAN_TPB; off <<= 1) {
        int u = (t >= off) ? sums[t - off] : 0;
        __syncthreads();
        sums[t] += u;
        __syncthreads();
    }
    int excl = sums[t] - s + partial[blockIdx.x];
#pragma unroll
    for (int j = 0; j < SCAN_VPT; ++j) {
        int i = base + j;
        if (i < N) { row_ptr[i] = excl; excl += vals[j]; }
    }
}

__global__ void fill_csr(const int* __restrict__ src, const int* __restrict__ dst,
                         const int* __restrict__ row_ptr, int* __restrict__ fill_cnt,
                         int* __restrict__ col, int E) {
    int i = blockIdx.x * blockDim.x + threadIdx.x;
    if (i < E) {
        int d = dst[i];
        int p = row_ptr[d] + atomicAdd(&fill_cnt[d], 1);
        col[p] = src[i];
    }
}

// hs_bf16[n][f] = bf16( dinv[n] * sum_k A[n][k] * W[k][f] )   (K = 128)
template <int BM, int F>
__global__ __launch_bounds__(256) void gemm_scale_bf16(
    const float* __restrict__ A, const float* __restrict__ W,
    const float* __restrict__ dinv, ushort_tt* __restrict__ out, int N) {
    constexpr int APAD = (F == 64) ? 4 : 0;
    __shared__ float As[BM][128 + APAD];
    __shared__ float Ws[128][F];
    const int tid = threadIdx.x;
    const int n0 = blockIdx.x * BM;

    for (int i = tid * 4; i < 128 * F; i += 256 * 4) {
        *(float4*)&((float*)Ws)[i] = *(const float4*)&W[i];
    }
    for (int i = tid * 4; i < BM * 128; i += 256 * 4) {
        int r = i >> 7, k = i & 127;
        int n = n0 + r;
        float4 v = make_float4(0.f, 0.f, 0.f, 0.f);
        if (n < N) v = *(const float4*)&A[n * 128 + k];
        *(float4*)&As[r][k] = v;
    }
    __syncthreads();

    constexpr int TC = F / 4;
    constexpr int TR = 256 / TC;
    constexpr int RPT = BM / TR;
    const int tc = tid % TC, tr = tid / TC;
    const int c0 = tc * 4;
    const int r0 = tr * RPT;

    float acc[RPT][4];
#pragma unroll
    for (int i = 0; i < RPT; ++i)
#pragma unroll
        for (int j = 0; j < 4; ++j) acc[i][j] = 0.f;

#pragma unroll 2
    for (int k4 = 0; k4 < 128; k4 += 4) {
        float4 a[RPT];
#pragma unroll
        for (int i = 0; i < RPT; ++i) a[i] = *(const float4*)&As[r0 + i][k4];
#pragma unroll
        for (int j = 0; j < 4; ++j) {
            float4 b = *(const float4*)&Ws[k4 + j][c0];
#pragma unroll
            for (int i = 0; i < RPT; ++i) {
                float aj = ((const float*)&a[i])[j];
                acc[i][0] += aj * b.x;
                acc[i][1] += aj * b.y;
                acc[i][2] += aj * b.z;
                acc[i][3] += aj * b.w;
            }
        }
    }

#pragma unroll
    for (int i = 0; i < RPT; ++i) {
        int n = n0 + r0 + i;
        if (n < N) {
            float s = dinv[n];
            ushort4 o;
            o.x = f2bf_rne(acc[i][0] * s);
            o.y = f2bf_rne(acc[i][1] * s);
            o.z = f2bf_rne(acc[i][2] * s);
            o.w = f2bf_rne(acc[i][3] * s);
            *(ushort4*)&out[(size_t)n * F + c0] = o;
        }
    }
}

__device__ __forceinline__ float4 ld4f(const float* p) { return *(const float4*)p; }

// One WAVE per node, bf16 rows. TPN = F/8 lanes per row (each lane loads
// dwordx4 = 8 bf16), NSEG = 64/TPN edge-parallel segments per wave.
// fp32 accumulate; butterfly shfl combine; fp32 output.
template <int F>
__global__ __launch_bounds__(256) void agg_elu_bf16(
    const ushort_tt* __restrict__ hs, const int* __restrict__ row_ptr,
    const int* __restrict__ col, const float* __restrict__ dinv,
    const float* __restrict__ bias, float* __restrict__ out, int N) {
    constexpr int TPN = F / 8;      // 16 @128, 8 @64
    constexpr int NSEG = 64 / TPN;  // 4, 8
    const int wave = threadIdx.x >> 6;
    const int lane = threadIdx.x & 63;
    const int seg = lane / TPN;
    const int t = lane % TPN;
    const int c0 = t * 8;
    const int n = blockIdx.x * 4 + wave;
    if (n >= N) return;

    const int e0 = row_ptr[n];
    const int e1 = row_ptr[n + 1];
    float acc[8];
#pragma unroll
    for (int j = 0; j < 8; ++j) acc[j] = 0.f;

    int e = e0 + seg;
    // 2 independent gathers in flight per lane (2*NSEG edges per iter)
    for (; e + NSEG < e1; e += 2 * NSEG) {
        int s0 = col[e];
        int s1 = col[e + NSEG];
        uint4 a0 = *(const uint4*)&hs[(size_t)s0 * F + c0];
        uint4 a1 = *(const uint4*)&hs[(size_t)s1 * F + c0];
        acc[0] += bflo(a0.x); acc[1] += bfhi(a0.x);
        acc[2] += bflo(a0.y); acc[3] += bfhi(a0.y);
        acc[4] += bflo(a0.z); acc[5] += bfhi(a0.z);
        acc[6] += bflo(a0.w); acc[7] += bfhi(a0.w);
        acc[0] += bflo(a1.x); acc[1] += bfhi(a1.x);
        acc[2] += bflo(a1.y); acc[3] += bfhi(a1.y);
        acc[4] += bflo(a1.z); acc[5] += bfhi(a1.z);
        acc[6] += bflo(a1.w); acc[7] += bfhi(a1.w);
    }
    for (; e < e1; e += NSEG) {
        uint4 a = *(const uint4*)&hs[(size_t)col[e] * F + c0];
        acc[0] += bflo(a.x); acc[1] += bfhi(a.x);
        acc[2] += bflo(a.y); acc[3] += bfhi(a.y);
        acc[4] += bflo(a.z); acc[5] += bfhi(a.z);
        acc[6] += bflo(a.w); acc[7] += bfhi(a.w);
    }

    // combine segments (same node, same columns) via butterfly
#pragma unroll
    for (int off = TPN; off < 64; off <<= 1)
#pragma unroll
        for (int j = 0; j < 8; ++j) acc[j] += __shfl_xor(acc[j], off, 64);

    if (seg == 0) {
        uint4 a = *(const uint4*)&hs[(size_t)n * F + c0];  // self-loop term
        acc[0] += bflo(a.x); acc[1] += bfhi(a.x);
        acc[2] += bflo(a.y); acc[3] += bfhi(a.y);
        acc[4] += bflo(a.z); acc[5] += bfhi(a.z);
        acc[6] += bflo(a.w); acc[7] += bfhi(a.w);
        const float s = dinv[n];
        float4 b0 = ld4f(&bias[c0]);
        float4 b1 = ld4f(&bias[c0 + 4]);
        float v[8];
        v[0] = s * acc[0] + b0.x; v[1] = s * acc[1] + b0.y;
        v[2] = s * acc[2] + b0.z; v[3] = s * acc[3] + b0.w;
        v[4] = s * acc[4] + b1.x; v[5] = s * acc[5] + b1.y;
        v[6] = s * acc[6] + b1.z; v[7] = s * acc[7] + b1.w;
#pragma unroll
        for (int j = 0; j < 8; ++j) v[j] = v[j] > 0.f ? v[j] : expm1f(v[j]);
        float4 o0 = make_float4(v[0], v[1], v[2], v[3]);
        float4 o1 = make_float4(v[4], v[5], v[6], v[7]);
        *(float4*)&out[(size_t)n * F + c0] = o0;
        *(float4*)&out[(size_t)n * F + c0 + 4] = o1;
    }
}

extern "C" void kernel_launch(void* const* d_in, const int* in_sizes, int n_in,
                              void* d_out, int out_size, void* d_ws, size_t ws_size,
                              hipStream_t stream) {
    const float* x  = (const float*)d_in[0];
    const int*   ei = (const int*)d_in[1];   // [2, E] int32
    const float* W1 = (const float*)d_in[2];
    const float* b1 = (const float*)d_in[3];
    const float* W2 = (const float*)d_in[4];
    const float* b2 = (const float*)d_in[5];
    float* out = (float*)d_out;

    const int N = in_sizes[0] / 128;
    const int E = in_sizes[1] / 2;
    const int* src = ei;
    const int* dst = ei + E;

    // workspace layout
    ushort_tt* hsA = (ushort_tt*)d_ws;                    // N*128 bf16 (hs1; reused for hs2 N*64)
    float* bufB = (float*)(hsA + (size_t)N * 128);        // N*128 floats (out1, fp32)
    float* deg  = bufB + (size_t)N * 128;                 // N
    float* dinv = deg + N;                                // N
    int* row_ptr  = (int*)(dinv + N);                     // N+1
    int* fill_cnt = row_ptr + N + 1;                      // N
    int* col      = fill_cnt + N;                         // E
    int* partial  = col + E;                              // scan partials

    const int TB = 256;
    const int gN = (N + TB - 1) / TB;
    const int gE = (E + TB - 1) / TB;
    const int nb = (N + SCAN_CHUNK - 1) / SCAN_CHUNK;

    init_deg_cnt<<<gN, TB, 0, stream>>>(deg, fill_cnt, N);
    count_deg<<<gE, TB, 0, stream>>>(dst, deg, E);
    deg_partial_dinv<<<nb, SCAN_TPB, 0, stream>>>(deg, dinv, partial, N);
    scan_partials<<<1, SCAN_TPB, 0, stream>>>(partial, row_ptr, nb, N);
    scan_write_rowptr<<<nb, SCAN_TPB, 0, stream>>>(deg, partial, row_ptr, N);
    fill_csr<<<gE, TB, 0, stream>>>(src, dst, row_ptr, fill_cnt, col, E);

    // layer 1: hs1(bf16) = (x@W1)*dinv ; out1(fp32) = elu(dinv*agg(hs1) + b1)
    gemm_scale_bf16<32, 128><<<(N + 31) / 32, 256, 0, stream>>>(x, W1, dinv, hsA, N);
    agg_elu_bf16<128><<<(N + 3) / 4, 256, 0, stream>>>(hsA, row_ptr, col, dinv, b1, bufB, N);

    // layer 2: hs2(bf16) = (out1@W2)*dinv ; out(fp32) = elu(dinv*agg(hs2) + b2)
    gemm_scale_bf16<64, 64><<<(N + 63) / 64, 256, 0, stream>>>(bufB, W2, dinv, hsA, N);
    agg_elu_bf16<64><<<(N + 3) / 4, 256, 0, stream>>>(hsA, row_ptr, col, dinv, b2, out, N);
}

// Round 6
// 500.369 us; speedup vs baseline: 1.9818x; 1.0290x over previous
//
#include <hip/hip_runtime.h>
#include <math.h>

// ---------------------------------------------------------------------------
// 2-layer GCN (PyG GCNConv semantics): self-loops, symmetric deg norm,
// linear, scatter-add aggregate, bias, ELU.
//   hs[n]  = (x @ W)[n] * dinv[n]      (stored bf16 — the gathered array)
//   out[n] = elu( dinv[n] * (hs[n] + sum_{e:dst=n} hs[src_e]) + b )
// CSR (by dst) rebuilt every call in d_ws.
// R1: agg gather float4 + 4x edge unroll.
// R2: 3-phase device-wide scan, dinv fused.
// R3: one wave per node, edge-parallel segments, shfl combine.
// R4: hs stored bf16 (halve the 8-XCD L2-fill supply wall).
// R5 (this): fill_csr -> XCD-striped scatter. R5 counters: WRITE_SIZE=107MB
//     = E*64B (random single-line writebacks, 16x amplification). Stripe
//     nodes (d>>11)&7 across XCDs via blockIdx%8 round-robin so each XCD's
//     col-window (~0.9MB) accumulates in its own L2 and writes back once.
//     dst/src scanned 8x but L3-resident; loaded nontemporal to not evict
//     the col windows from L2.
// ---------------------------------------------------------------------------

#define SCAN_TPB 256
#define SCAN_VPT 4
#define SCAN_CHUNK (SCAN_TPB * SCAN_VPT)  // 1024 elements per block

typedef unsigned int uint32_tt;
typedef unsigned short ushort_tt;

__device__ __forceinline__ ushort_tt f2bf_rne(float f) {
    uint32_tt u = __float_as_uint(f);
    u += 0x7FFFu + ((u >> 16) & 1u);  // round-to-nearest-even
    return (ushort_tt)(u >> 16);
}
__device__ __forceinline__ float bflo(uint32_tt u) { return __uint_as_float(u << 16); }
__device__ __forceinline__ float bfhi(uint32_tt u) { return __uint_as_float(u & 0xFFFF0000u); }

__global__ void init_deg_cnt(float* __restrict__ deg, int* __restrict__ fill_cnt, int N) {
    int i = blockIdx.x * blockDim.x + threadIdx.x;
    if (i < N) { deg[i] = 1.0f; fill_cnt[i] = 0; }
}

__global__ void count_deg(const int* __restrict__ dst, float* __restrict__ deg, int E) {
    int i = blockIdx.x * blockDim.x + threadIdx.x;
    if (i < E) atomicAdd(&deg[__builtin_nontemporal_load(&dst[i])], 1.0f);
}

// Scan phase 1: per-block sum of (deg[i]-1) -> partial[b]; fused dinv.
__global__ __launch_bounds__(SCAN_TPB) void deg_partial_dinv(
    const float* __restrict__ deg, float* __restrict__ dinv,
    int* __restrict__ partial, int N) {
    const int t = threadIdx.x;
    const int base = blockIdx.x * SCAN_CHUNK + t * SCAN_VPT;
    int s = 0;
#pragma unroll
    for (int j = 0; j < SCAN_VPT; ++j) {
        int i = base + j;
        if (i < N) {
            float d = deg[i];
            dinv[i] = rsqrtf(d);
            s += (int)d - 1;
        }
    }
    __shared__ int sums[SCAN_TPB];
    sums[t] = s;
    __syncthreads();
    for (int off = SCAN_TPB / 2; off > 0; off >>= 1) {
        if (t < off) sums[t] += sums[t + off];
        __syncthreads();
    }
    if (t == 0) partial[blockIdx.x] = sums[0];
}

// Scan phase 2: exclusive scan of partials (nb <= 256), write row_ptr[N]=E.
__global__ __launch_bounds__(SCAN_TPB) void scan_partials(
    int* __restrict__ partial, int* __restrict__ row_ptr, int nb, int N) {
    __shared__ int sh[SCAN_TPB];
    const int t = threadIdx.x;
    int v = (t < nb) ? partial[t] : 0;
    sh[t] = v;
    __syncthreads();
    for (int off = 1; off < SCAN_TPB; off <<= 1) {
        int u = (t >= off) ? sh[t - off] : 0;
        __syncthreads();
        sh[t] += u;
        __syncthreads();
    }
    if (t < nb) partial[t] = sh[t] - v;
    if (t == 0) row_ptr[N] = sh[nb - 1];
}

// Scan phase 3: intra-block exclusive scan + block offset -> row_ptr[i].
__global__ __launch_bounds__(SCAN_TPB) void scan_write_rowptr(
    const float* __restrict__ deg, const int* __restrict__ partial,
    int* __restrict__ row_ptr, int N) {
    const int t = threadIdx.x;
    const int base = blockIdx.x * SCAN_CHUNK + t * SCAN_VPT;
    int vals[SCAN_VPT];
    int s = 0;
#pragma unroll
    for (int j = 0; j < SCAN_VPT; ++j) {
        int i = base + j;
        vals[j] = (i < N) ? (int)deg[i] - 1 : 0;
        s += vals[j];
    }
    __shared__ int sums[SCAN_TPB];
    sums[t] = s;
    __syncthreads();
    for (int off = 1; off < SCAN_TPB; off <<= 1) {
        int u = (t >= off) ? sums[t - off] : 0;
        __syncthreads();
        sums[t] += u;
        __syncthreads();
    }
    int excl = sums[t] - s + partial[blockIdx.x];
#pragma unroll
    for (int j = 0; j < SCAN_VPT; ++j) {
        int i = base + j;
        if (i < N) { row_ptr[i] = excl; excl += vals[j]; }
    }
}

// XCD-striped CSR fill. Block b (-> XCD b%8 by dispatch round-robin) scans
// edge chunk b>>3 and keeps edges whose dst stripe ((d>>11)&7) == b%8.
// Col writes then stay in one XCD's L2 until lines are full.
__global__ __launch_bounds__(256) void fill_csr_xcd(
    const int* __restrict__ src, const int* __restrict__ dst,
    const int* __restrict__ row_ptr, int* __restrict__ fill_cnt,
    int* __restrict__ col, int E, int per) {
    const int me = blockIdx.x & 7;
    const int chunk = blockIdx.x >> 3;
    const int lo = chunk * per;
    const int hi = min(lo + per, E);
    for (int i = lo + (int)threadIdx.x; i < hi; i += 256) {
        int d = __builtin_nontemporal_load(&dst[i]);
        if (((d >> 11) & 7) == me) {
            int s = __builtin_nontemporal_load(&src[i]);
            int p = row_ptr[d] + atomicAdd(&fill_cnt[d], 1);
            col[p] = s;
        }
    }
}

// hs_bf16[n][f] = bf16( dinv[n] * sum_k A[n][k] * W[k][f] )   (K = 128)
template <int BM, int F>
__global__ __launch_bounds__(256) void gemm_scale_bf16(
    const float* __restrict__ A, const float* __restrict__ W,
    const float* __restrict__ dinv, ushort_tt* __restrict__ out, int N) {
    constexpr int APAD = (F == 64) ? 4 : 0;
    __shared__ float As[BM][128 + APAD];
    __shared__ float Ws[128][F];
    const int tid = threadIdx.x;
    const int n0 = blockIdx.x * BM;

    for (int i = tid * 4; i < 128 * F; i += 256 * 4) {
        *(float4*)&((float*)Ws)[i] = *(const float4*)&W[i];
    }
    for (int i = tid * 4; i < BM * 128; i += 256 * 4) {
        int r = i >> 7, k = i & 127;
        int n = n0 + r;
        float4 v = make_float4(0.f, 0.f, 0.f, 0.f);
        if (n < N) v = *(const float4*)&A[n * 128 + k];
        *(float4*)&As[r][k] = v;
    }
    __syncthreads();

    constexpr int TC = F / 4;
    constexpr int TR = 256 / TC;
    constexpr int RPT = BM / TR;
    const int tc = tid % TC, tr = tid / TC;
    const int c0 = tc * 4;
    const int r0 = tr * RPT;

    float acc[RPT][4];
#pragma unroll
    for (int i = 0; i < RPT; ++i)
#pragma unroll
        for (int j = 0; j < 4; ++j) acc[i][j] = 0.f;

#pragma unroll 2
    for (int k4 = 0; k4 < 128; k4 += 4) {
        float4 a[RPT];
#pragma unroll
        for (int i = 0; i < RPT; ++i) a[i] = *(const float4*)&As[r0 + i][k4];
#pragma unroll
        for (int j = 0; j < 4; ++j) {
            float4 b = *(const float4*)&Ws[k4 + j][c0];
#pragma unroll
            for (int i = 0; i < RPT; ++i) {
                float aj = ((const float*)&a[i])[j];
                acc[i][0] += aj * b.x;
                acc[i][1] += aj * b.y;
                acc[i][2] += aj * b.z;
                acc[i][3] += aj * b.w;
            }
        }
    }

#pragma unroll
    for (int i = 0; i < RPT; ++i) {
        int n = n0 + r0 + i;
        if (n < N) {
            float s = dinv[n];
            ushort4 o;
            o.x = f2bf_rne(acc[i][0] * s);
            o.y = f2bf_rne(acc[i][1] * s);
            o.z = f2bf_rne(acc[i][2] * s);
            o.w = f2bf_rne(acc[i][3] * s);
            *(ushort4*)&out[(size_t)n * F + c0] = o;
        }
    }
}

__device__ __forceinline__ float4 ld4f(const float* p) { return *(const float4*)p; }

// One WAVE per node, bf16 rows. TPN = F/8 lanes per row (dwordx4 = 8 bf16),
// NSEG = 64/TPN edge-parallel segments. fp32 accumulate; shfl combine.
template <int F>
__global__ __launch_bounds__(256) void agg_elu_bf16(
    const ushort_tt* __restrict__ hs, const int* __restrict__ row_ptr,
    const int* __restrict__ col, const float* __restrict__ dinv,
    const float* __restrict__ bias, float* __restrict__ out, int N) {
    constexpr int TPN = F / 8;      // 16 @128, 8 @64
    constexpr int NSEG = 64 / TPN;  // 4, 8
    const int wave = threadIdx.x >> 6;
    const int lane = threadIdx.x & 63;
    const int seg = lane / TPN;
    const int t = lane % TPN;
    const int c0 = t * 8;
    const int n = blockIdx.x * 4 + wave;
    if (n >= N) return;

    const int e0 = row_ptr[n];
    const int e1 = row_ptr[n + 1];
    float acc[8];
#pragma unroll
    for (int j = 0; j < 8; ++j) acc[j] = 0.f;

    int e = e0 + seg;
    for (; e + NSEG < e1; e += 2 * NSEG) {
        int s0 = col[e];
        int s1 = col[e + NSEG];
        uint4 a0 = *(const uint4*)&hs[(size_t)s0 * F + c0];
        uint4 a1 = *(const uint4*)&hs[(size_t)s1 * F + c0];
        acc[0] += bflo(a0.x); acc[1] += bfhi(a0.x);
        acc[2] += bflo(a0.y); acc[3] += bfhi(a0.y);
        acc[4] += bflo(a0.z); acc[5] += bfhi(a0.z);
        acc[6] += bflo(a0.w); acc[7] += bfhi(a0.w);
        acc[0] += bflo(a1.x); acc[1] += bfhi(a1.x);
        acc[2] += bflo(a1.y); acc[3] += bfhi(a1.y);
        acc[4] += bflo(a1.z); acc[5] += bfhi(a1.z);
        acc[6] += bflo(a1.w); acc[7] += bfhi(a1.w);
    }
    for (; e < e1; e += NSEG) {
        uint4 a = *(const uint4*)&hs[(size_t)col[e] * F + c0];
        acc[0] += bflo(a.x); acc[1] += bfhi(a.x);
        acc[2] += bflo(a.y); acc[3] += bfhi(a.y);
        acc[4] += bflo(a.z); acc[5] += bfhi(a.z);
        acc[6] += bflo(a.w); acc[7] += bfhi(a.w);
    }

#pragma unroll
    for (int off = TPN; off < 64; off <<= 1)
#pragma unroll
        for (int j = 0; j < 8; ++j) acc[j] += __shfl_xor(acc[j], off, 64);

    if (seg == 0) {
        uint4 a = *(const uint4*)&hs[(size_t)n * F + c0];  // self-loop term
        acc[0] += bflo(a.x); acc[1] += bfhi(a.x);
        acc[2] += bflo(a.y); acc[3] += bfhi(a.y);
        acc[4] += bflo(a.z); acc[5] += bfhi(a.z);
        acc[6] += bflo(a.w); acc[7] += bfhi(a.w);
        const float s = dinv[n];
        float4 b0 = ld4f(&bias[c0]);
        float4 b1 = ld4f(&bias[c0 + 4]);
        float v[8];
        v[0] = s * acc[0] + b0.x; v[1] = s * acc[1] + b0.y;
        v[2] = s * acc[2] + b0.z; v[3] = s * acc[3] + b0.w;
        v[4] = s * acc[4] + b1.x; v[5] = s * acc[5] + b1.y;
        v[6] = s * acc[6] + b1.z; v[7] = s * acc[7] + b1.w;
#pragma unroll
        for (int j = 0; j < 8; ++j) v[j] = v[j] > 0.f ? v[j] : expm1f(v[j]);
        float4 o0 = make_float4(v[0], v[1], v[2], v[3]);
        float4 o1 = make_float4(v[4], v[5], v[6], v[7]);
        *(float4*)&out[(size_t)n * F + c0] = o0;
        *(float4*)&out[(size_t)n * F + c0 + 4] = o1;
    }
}

extern "C" void kernel_launch(void* const* d_in, const int* in_sizes, int n_in,
                              void* d_out, int out_size, void* d_ws, size_t ws_size,
                              hipStream_t stream) {
    const float* x  = (const float*)d_in[0];
    const int*   ei = (const int*)d_in[1];   // [2, E] int32
    const float* W1 = (const float*)d_in[2];
    const float* b1 = (const float*)d_in[3];
    const float* W2 = (const float*)d_in[4];
    const float* b2 = (const float*)d_in[5];
    float* out = (float*)d_out;

    const int N = in_sizes[0] / 128;
    const int E = in_sizes[1] / 2;
    const int* src = ei;
    const int* dst = ei + E;

    // workspace layout
    ushort_tt* hsA = (ushort_tt*)d_ws;                    // N*128 bf16 (hs1; reused for hs2 N*64)
    float* bufB = (float*)(hsA + (size_t)N * 128);        // N*128 floats (out1, fp32)
    float* deg  = bufB + (size_t)N * 128;                 // N
    float* dinv = deg + N;                                // N
    int* row_ptr  = (int*)(dinv + N);                     // N+1
    int* fill_cnt = row_ptr + N + 1;                      // N
    int* col      = fill_cnt + N;                         // E
    int* partial  = col + E;                              // scan partials

    const int TB = 256;
    const int gN = (N + TB - 1) / TB;
    const int gE = (E + TB - 1) / TB;
    const int nb = (N + SCAN_CHUNK - 1) / SCAN_CHUNK;

    init_deg_cnt<<<gN, TB, 0, stream>>>(deg, fill_cnt, N);
    count_deg<<<gE, TB, 0, stream>>>(dst, deg, E);
    deg_partial_dinv<<<nb, SCAN_TPB, 0, stream>>>(deg, dinv, partial, N);
    scan_partials<<<1, SCAN_TPB, 0, stream>>>(partial, row_ptr, nb, N);
    scan_write_rowptr<<<nb, SCAN_TPB, 0, stream>>>(deg, partial, row_ptr, N);

    const int FCHUNKS = 256;
    const int per = (E + FCHUNKS - 1) / FCHUNKS;
    fill_csr_xcd<<<8 * FCHUNKS, 256, 0, stream>>>(src, dst, row_ptr, fill_cnt, col, E, per);

    // layer 1: hs1(bf16) = (x@W1)*dinv ; out1(fp32) = elu(dinv*agg(hs1) + b1)
    gemm_scale_bf16<32, 128><<<(N + 31) / 32, 256, 0, stream>>>(x, W1, dinv, hsA, N);
    agg_elu_bf16<128><<<(N + 3) / 4, 256, 0, stream>>>(hsA, row_ptr, col, dinv, b1, bufB, N);

    // layer 2: hs2(bf16) = (out1@W2)*dinv ; out(fp32) = elu(dinv*agg(hs2) + b2)
    gemm_scale_bf16<64, 64><<<(N + 63) / 64, 256, 0, stream>>>(bufB, W2, dinv, hsA, N);
    agg_elu_bf16<64><<<(N + 3) / 4, 256, 0, stream>>>(hsA, row_ptr, col, dinv, b2, out, N);
}